// Round 9
// baseline (360.501 us; speedup 1.0000x reference)
//
#include <hip/hip_runtime.h>
#include <math.h>

#define DEVFN __device__ __forceinline__

typedef __attribute__((ext_vector_type(4))) float f32x4;
typedef __attribute__((ext_vector_type(8))) __bf16 bf16x8;
typedef __attribute__((ext_vector_type(8))) short short8v;

#define NB   64
#define TXD  1024
#define NHD  512
#define HSZ  512
#define ESZ  300
#define VSZ  32000
#define G4   (4*HSZ)           // 2048
#define KPRE (ESZ + NHD + HSZ) // 1324 (emb|c_prev|h0)
#define KPOST 1536             // (h0out|ctx|h1)
#define HALFD 512

DEVFN short f2bf(float f) {
  unsigned u = __float_as_uint(f);
  u = (u + 0x7fffu + ((u >> 16) & 1u)) >> 16;
  return (short)u;
}
DEVFN float sigm(float x) { return 1.0f / (1.0f + __expf(-x)); }

DEVFN short8v pack8(float4 a, float4 b) {
  short8v v;
  v[0]=f2bf(a.x); v[1]=f2bf(a.y); v[2]=f2bf(a.z); v[3]=f2bf(a.w);
  v[4]=f2bf(b.x); v[5]=f2bf(b.y); v[6]=f2bf(b.z); v[7]=f2bf(b.w);
  return v;
}
// async global->LDS, 16B per lane: dest = wave-uniform base + lane*16
DEVFN void gload16(const void* g, void* lds_base) {
  __builtin_amdgcn_global_load_lds(
      (const __attribute__((address_space(1))) unsigned int*)g,
      (__attribute__((address_space(3))) unsigned int*)lds_base, 16, 0, 0);
}

DEVFN float4 ldA4(const float* __restrict__ A, int lda, int row, int k, int Ka) {
  if (k >= Ka) { float4 z = {0.f,0.f,0.f,0.f}; return z; }
  return *(const float4*)(A + (size_t)row * lda + k);
}
DEVFN float4 ldB4(const float* __restrict__ B1, int ldb1, int split,
                  const float* __restrict__ B2, int ldb2, int row, int k, int Ka) {
  if (k >= Ka) { float4 z = {0.f,0.f,0.f,0.f}; return z; }
  if (k < split) return *(const float4*)(B1 + (size_t)row * ldb1 + k);
  return *(const float4*)(B2 + (size_t)row * ldb2 + (k - split));
}

// ---------- prep: W1->bf16 (blocks 0..127) | pre concat (128..458) --------------
__global__ __launch_bounds__(256)
void prep(const int* __restrict__ yt, const float* __restrict__ embW,
          const float* __restrict__ c_prev, const float* __restrict__ h0,
          const float* __restrict__ W1, unsigned short* __restrict__ W1b,
          float* __restrict__ cat)
{
  int b = blockIdx.x;
  if (b < 128) {
    int i = b * 256 + threadIdx.x;            // 0..32767, 8 elems each
    int c = i >> 6, kq = (i & 63) * 8;
    float4 a = *(const float4*)(W1 + (size_t)c * 1024 + kq);
    float4 bb = *(const float4*)(W1 + (size_t)c * 1024 + kq + 4);
    *(short8v*)(W1b + (size_t)c * 512 + kq) = pack8(a, bb);
  } else {
    int i = (b - 128) * 256 + threadIdx.x;    // < 64*1324
    if (i >= NB * KPRE) return;
    int n = i / KPRE, c = i - n * KPRE;
    float v;
    if (c < ESZ)            v = embW[(size_t)yt[n] * ESZ + c];
    else if (c < ESZ + NHD) v = c_prev[(size_t)n * NHD + (c - ESZ)];
    else                    v = h0[(size_t)n * HSZ + (c - ESZ - NHD)];
    cat[i] = v;
  }
}

// ---------- generic MFMA GEMM, 128-col tiles: C[64 x N] = A[64 x K] B[N x K]^T --
// Kslice multiple of 32. Split-K partial at C + ks*64*ldc.
// EPI: 0 none, 4 relu(x+bias1) + fused BN scale/shift outputs.
template<int EPI>
__global__ __launch_bounds__(256)
void mfma_gemm128(const float* __restrict__ A, int lda, int Ka,
                  const float* __restrict__ B1, int ldb1, int split,
                  const float* __restrict__ B2, int ldb2,
                  const float* __restrict__ bias1,
                  float* __restrict__ C, int ldc, int Kslice,
                  const float* __restrict__ gamma, const float* __restrict__ beta,
                  float* __restrict__ bnsc, float* __restrict__ bnsh)
{
  __shared__ __align__(16) short As[64][40];
  __shared__ __align__(16) short Bs[128][40];
  const int tid = threadIdx.x;
  const int w = tid >> 6, lane = tid & 63;
  const int wr = w >> 1, wc = w & 1;
  const int cl = lane & 15, g = lane >> 4;
  const int n0 = blockIdx.x * 128;
  const int ks = blockIdx.y;
  const int kbeg = ks * Kslice;
  const int kend = min(kbeg + Kslice, Ka);
  C += (size_t)ks * 64 * ldc;

  const f32x4 fz = {0.f,0.f,0.f,0.f};
  f32x4 acc[2][4];
  #pragma unroll
  for (int i = 0; i < 2; ++i)
    #pragma unroll
    for (int j = 0; j < 4; ++j) acc[i][j] = fz;

  const int sr  = tid >> 2;        // 0..63
  const int skc = (tid & 3) * 8;   // 0,8,16,24

  float4 ra0, ra1, rb0[2], rb1[2];
  ra0 = ldA4(A, lda, sr, kbeg + skc, Ka);
  ra1 = ldA4(A, lda, sr, kbeg + skc + 4, Ka);
  #pragma unroll
  for (int it = 0; it < 2; ++it) {
    rb0[it] = ldB4(B1, ldb1, split, B2, ldb2, n0 + sr + it*64, kbeg + skc, Ka);
    rb1[it] = ldB4(B1, ldb1, split, B2, ldb2, n0 + sr + it*64, kbeg + skc + 4, Ka);
  }

  for (int k0 = kbeg; k0 < kend; k0 += 32) {
    __syncthreads();
    *(short8v*)&As[sr][skc] = pack8(ra0, ra1);
    #pragma unroll
    for (int it = 0; it < 2; ++it)
      *(short8v*)&Bs[sr + it*64][skc] = pack8(rb0[it], rb1[it]);
    __syncthreads();
    if (k0 + 32 < kend) {
      ra0 = ldA4(A, lda, sr, k0 + 32 + skc, Ka);
      ra1 = ldA4(A, lda, sr, k0 + 32 + skc + 4, Ka);
      #pragma unroll
      for (int it = 0; it < 2; ++it) {
        rb0[it] = ldB4(B1, ldb1, split, B2, ldb2, n0 + sr + it*64, k0 + 32 + skc, Ka);
        rb1[it] = ldB4(B1, ldb1, split, B2, ldb2, n0 + sr + it*64, k0 + 32 + skc + 4, Ka);
      }
    }
    bf16x8 af[2], bfr[4];
    #pragma unroll
    for (int mi = 0; mi < 2; ++mi)
      af[mi] = *(const bf16x8*)&As[wr*32 + mi*16 + cl][g * 8];
    #pragma unroll
    for (int ni = 0; ni < 4; ++ni)
      bfr[ni] = *(const bf16x8*)&Bs[wc*64 + ni*16 + cl][g * 8];
    #pragma unroll
    for (int mi = 0; mi < 2; ++mi)
      #pragma unroll
      for (int ni = 0; ni < 4; ++ni)
        acc[mi][ni] = __builtin_amdgcn_mfma_f32_16x16x32_bf16(af[mi], bfr[ni], acc[mi][ni], 0, 0, 0);
  }

  float s1[4] = {0.f,0.f,0.f,0.f}, s2[4] = {0.f,0.f,0.f,0.f};
  #pragma unroll
  for (int ni = 0; ni < 4; ++ni) {
    int nn = n0 + wc*64 + ni*16 + cl;
    float b = (EPI == 4) ? bias1[nn] : 0.f;
    #pragma unroll
    for (int mi = 0; mi < 2; ++mi)
      #pragma unroll
      for (int r = 0; r < 4; ++r) {
        int m = wr*32 + mi*16 + g*4 + r;
        float v = acc[mi][ni][r];
        if (EPI == 4) v = fmaxf(v + b, 0.f);
        C[(size_t)m * ldc + nn] = v;
        if (EPI == 4) { s1[ni] += v; s2[ni] = fmaf(v, v, s2[ni]); }
      }
  }
  if (EPI == 4) {
    #pragma unroll
    for (int mm = 16; mm < 64; mm <<= 1)
      #pragma unroll
      for (int ni = 0; ni < 4; ++ni) {
        s1[ni] += __shfl_xor(s1[ni], mm, 64);
        s2[ni] += __shfl_xor(s2[ni], mm, 64);
      }
    float* red = (float*)As;   // 2KB, staging dead
    __syncthreads();
    if (g == 0) {
      #pragma unroll
      for (int ni = 0; ni < 4; ++ni) {
        int col = wc*64 + ni*16 + cl;
        red[(wr*128 + col)*2 + 0] = s1[ni];
        red[(wr*128 + col)*2 + 1] = s2[ni];
      }
    }
    __syncthreads();
    if (tid < 128) {
      int col = n0 + tid;
      float a1 = red[tid*2] + red[(128 + tid)*2];
      float a2 = red[tid*2 + 1] + red[(128 + tid)*2 + 1];
      float mean = a1 * (1.0f / NB);
      float var = a2 * (1.0f / NB) - mean * mean;
      float rr = rsqrtf(var + 1e-5f);
      float sc = gamma[col] * rr;
      bnsc[col] = sc;
      bnsh[col] = beta[col] - mean * sc;
    }
  }
}

// ---------- LSTM pointwise, summing np split-K gate partials --------------------
__global__ __launch_bounds__(256)
void lstm_point2(const float* __restrict__ gp, int np,
                 const float* __restrict__ bih, const float* __restrict__ bhh,
                 const float* __restrict__ c_old,
                 float* __restrict__ h_new, float* __restrict__ c_new)
{
  int i = blockIdx.x * 256 + threadIdx.x;   // < 64*512
  int n = i >> 9, k = i & 511;
  float g[4];
  #pragma unroll
  for (int j = 0; j < 4; ++j) {
    int idx = j * 512 + k;
    float s = bih[idx] + bhh[idx];
    for (int ks = 0; ks < np; ++ks)
      s += gp[((size_t)ks*64 + n) * G4 + idx];
    g[j] = s;
  }
  float c = sigm(g[1]) * c_old[i] + sigm(g[0]) * tanhf(g[2]);
  float h = sigm(g[3]) * tanhf(c);
  h_new[i] = h; c_new[i] = c;
}

// ---------- fused attention: 128 rows x ALL 512 cols, 8 waves, 2-stage ----------
// grid 512 row-tiles; 2 blocks/CU (80 KB LDS). Wave grid 2r x 4c, wave tile
// 64x128, acc 4x8. Zero-conflict layout (R7-proven): line=row>>1 (128B),
// half=row&1, slot16 = g ^ (line&3). A reg-staged bf16 (pack at write, AFTER
// MFMAs); B via pre-swizzled gload16. Epilogue: softmax(local 128) + context.
__global__ __launch_bounds__(512, 4)
void att_fused(const float* __restrict__ enc, const unsigned short* __restrict__ W1b,
               const float* __restrict__ W2, const float* __restrict__ sprojp,
               const float* __restrict__ b1,
               float* __restrict__ mbuf, float* __restrict__ sbuf,
               float* __restrict__ ctxp)
{
  __shared__ __align__(16) char smem[81920];  // A 2x8KB @0, B 2x32KB @16384
  const int tid = threadIdx.x;
  const int wid = tid >> 6, lane = tid & 63;
  const int wr = wid >> 2, wc = wid & 3;
  const int cl = lane & 15, g = lane >> 4;
  const int rt = blockIdx.x;
  const int r0 = rt << 7;
  const int n  = rt >> 3;

  // A write decode: row = tid>>2 (0..127), slot = tid&3
  const int a_row = tid >> 2;
  const int a_line = a_row >> 1;
  const int a_waddr = a_line*128 + (a_row & 1)*64 + (((tid & 3) ^ (a_line & 3)) << 4);
  // B gload lane decode (dest = base + lane*16, pre-swizzled source)
  const int b_r = ((lane >> 3) << 1) + ((lane >> 2) & 1);    // 0..15
  const int b_q = (((lane & 3) ^ ((lane >> 3) & 3)) << 3);   // bf16 units

  const f32x4 fz = {0.f,0.f,0.f,0.f};
  f32x4 acc[4][8];
  #pragma unroll
  for (int mi = 0; mi < 4; ++mi)
    #pragma unroll
    for (int ni = 0; ni < 8; ++ni) acc[mi][ni] = fz;

  float4 a_lo, a_hi;
  #define A_LOAD(tt) do { \
    const float* asrc = enc + (size_t)(r0 + a_row) * 512 + (tt) * 32 + (tid & 3) * 8; \
    a_lo = *(const float4*)asrc; a_hi = *(const float4*)(asrc + 4); } while (0)
  #define A_WRITE(buf) \
    *(short8v*)(smem + (buf) * 8192 + a_waddr) = pack8(a_lo, a_hi)
  #define STAGE_B(buf, tt) do { int k0 = (tt) * 32; \
    _Pragma("unroll") \
    for (int jj = 0; jj < 4; ++jj) { int j = (wid << 2) + jj; \
      gload16(W1b + (size_t)((j << 4) + b_r) * 512 + k0 + b_q, \
              smem + 16384 + (buf) * 32768 + (j << 10)); } } while (0)

  // prologue
  A_LOAD(0);
  STAGE_B(0, 0);
  A_WRITE(0);
  __syncthreads();

  for (int t = 0; t < 16; ++t) {
    const int s = t & 1;
    if (t < 15) { A_LOAD(t + 1); STAGE_B(s ^ 1, t + 1); }
    const char* Ab = smem + s * 8192;
    const char* Bb = smem + 16384 + s * 32768;
    bf16x8 af[4];
    #pragma unroll
    for (int mi = 0; mi < 4; ++mi) {
      int r = wr * 64 + mi * 16 + cl;
      af[mi] = *(const bf16x8*)(Ab + (r >> 1) * 128 + (r & 1) * 64
                                + ((g ^ ((r >> 1) & 3)) << 4));
    }
    #pragma unroll
    for (int ni = 0; ni < 8; ++ni) {
      int r = wc * 128 + ni * 16 + cl;
      bf16x8 bf = *(const bf16x8*)(Bb + (r >> 1) * 128 + (r & 1) * 64
                                   + ((g ^ ((r >> 1) & 3)) << 4));
      #pragma unroll
      for (int mi = 0; mi < 4; ++mi)
        acc[mi][ni] = __builtin_amdgcn_mfma_f32_16x16x32_bf16(af[mi], bf, acc[mi][ni], 0, 0, 0);
    }
    if (t < 15) A_WRITE(s ^ 1);   // pack+write AFTER MFMAs: A latency hidden
    __syncthreads();
  }
  #undef A_LOAD
  #undef A_WRITE
  #undef STAGE_B

  // epilogue: relu(acc + sproj + b1) * W2, reduce over this wave's 128 cols
  float part[4][4] = {};
  #pragma unroll
  for (int ni = 0; ni < 8; ++ni) {
    int c = wc*128 + ni*16 + cl;
    float spv = b1[c];
    #pragma unroll
    for (int ks = 0; ks < 4; ++ks)
      spv += sprojp[((size_t)ks*64 + n) * HALFD + c];
    float w2 = W2[c];
    #pragma unroll
    for (int mi = 0; mi < 4; ++mi)
      #pragma unroll
      for (int r = 0; r < 4; ++r)
        part[mi][r] += fmaxf(acc[mi][ni][r] + spv, 0.f) * w2;
  }
  #pragma unroll
  for (int mm = 1; mm < 16; mm <<= 1)
    #pragma unroll
    for (int mi = 0; mi < 4; ++mi)
      #pragma unroll
      for (int r = 0; r < 4; ++r)
        part[mi][r] += __shfl_xor(part[mi][r], mm, 64);
  float* red = (float*)smem;            // [8][64] @0 (2 KB)
  float* sc  = (float*)(smem + 2048);   // [128]
  float* eV  = (float*)(smem + 2560);   // [128]
  if (cl == 0) {
    #pragma unroll
    for (int mi = 0; mi < 4; ++mi)
      #pragma unroll
      for (int r = 0; r < 4; ++r)
        red[wid*64 + mi*16 + g*4 + r] = part[mi][r];
  }
  __syncthreads();
  if (tid < 128) {
    int h = tid >> 6, idx = tid & 63;   // h = wr
    sc[tid] = red[(h*4 + 0)*64 + idx] + red[(h*4 + 1)*64 + idx]
            + red[(h*4 + 2)*64 + idx] + red[(h*4 + 3)*64 + idx];
  }
  __syncthreads();
  if (tid < 64) {
    float s0 = sc[tid], s1v = sc[tid + 64];
    float M = fmaxf(s0, s1v);
    #pragma unroll
    for (int mm = 32; mm >= 1; mm >>= 1) M = fmaxf(M, __shfl_xor(M, mm, 64));
    float e0 = __expf(s0 - M), e1 = __expf(s1v - M);
    eV[tid] = e0; eV[tid + 64] = e1;
    float S = e0 + e1;
    #pragma unroll
    for (int mm = 32; mm >= 1; mm >>= 1) S += __shfl_xor(S, mm, 64);
    if (tid == 0) { mbuf[rt] = M; sbuf[rt] = S; }
  }
  __syncthreads();

  // pass 2: ctx_rt[c] = sum_{t<128} eV[t] * enc[r0+t][c]  (rows L2-hot)
  f32x4* red4 = (f32x4*)(smem + 16384);   // [4][128] f32x4 (8 KB)
  {
    const int cgrp = tid & 127, tq = tid >> 7;   // tq 0..3, 32 rows each
    const float* ebase = enc + (size_t)r0 * 512 + (cgrp << 2);
    f32x4 a4 = fz;
    #pragma unroll 8
    for (int tt = 0; tt < 32; ++tt) {
      int t = tq*32 + tt;
      float et = eV[t];
      float4 x = *(const float4*)(ebase + (size_t)t * 512);
      a4[0] = fmaf(et, x.x, a4[0]);
      a4[1] = fmaf(et, x.y, a4[1]);
      a4[2] = fmaf(et, x.z, a4[2]);
      a4[3] = fmaf(et, x.w, a4[3]);
    }
    red4[tq*128 + cgrp] = a4;
  }
  __syncthreads();
  if (tid < 128) {
    f32x4 s4 = red4[tid];
    f32x4 b4 = red4[128 + tid];
    f32x4 c4 = red4[256 + tid];
    f32x4 d4 = red4[384 + tid];
    f32x4 o4;
    #pragma unroll
    for (int i = 0; i < 4; ++i) o4[i] = s4[i] + b4[i] + c4[i] + d4[i];
    *(f32x4*)(ctxp + (size_t)rt * 512 + tid*4) = o4;
  }
}

// ---------- combine 8 tile-partials per n -> context, post concat ---------------
__global__ __launch_bounds__(256)
void att_combine(const float* __restrict__ mbuf, const float* __restrict__ sbuf,
                 const float* __restrict__ ctxp, const float* __restrict__ h0out,
                 const float* __restrict__ h1in,
                 float* __restrict__ ctx_out, float* __restrict__ cat)
{
  int i = blockIdx.x * 256 + threadIdx.x;   // < 64*512
  int n = i >> 9, c = i & 511;
  float M = -1e30f;
  #pragma unroll
  for (int b = 0; b < 8; ++b) M = fmaxf(M, mbuf[n*8 + b]);
  float S = 0.f, ctx = 0.f;
  #pragma unroll
  for (int b = 0; b < 8; ++b) {
    float w = __expf(mbuf[n*8 + b] - M);
    S = fmaf(sbuf[n*8 + b], w, S);
    ctx = fmaf(ctxp[(size_t)(n*8 + b)*512 + c], w, ctx);
  }
  ctx /= S;
  ctx_out[i] = ctx;
  cat[(size_t)n * KPOST + c] = h0out[i];
  cat[(size_t)n * KPOST + HSZ + c] = ctx;
  cat[(size_t)n * KPOST + 2*HSZ + c] = h1in[i];
}

// ---------- final softmax over V: z cached in registers (1 read pass) -----------
__global__ __launch_bounds__(1024)
void softmax_v(const float* __restrict__ z, const float* __restrict__ scale,
               const float* __restrict__ shift, float* __restrict__ out)
{
  int n = blockIdx.x, tid = threadIdx.x;
  const float* zr = z + (size_t)n * VSZ;
  float* orow = out + (size_t)n * VSZ;
  __shared__ float rb[16];
  __shared__ float sb[16];
  float v[32]; float mx = -1e30f;
  #pragma unroll
  for (int i = 0; i < 32; ++i) {
    int j = tid + i*1024;
    v[i] = (j < VSZ) ? fmaf(zr[j], scale[j], shift[j]) : -1e30f;
    mx = fmaxf(mx, v[i]);
  }
  #pragma unroll
  for (int m = 32; m >= 1; m >>= 1) mx = fmaxf(mx, __shfl_xor(mx, m, 64));
  if ((tid & 63) == 0) rb[tid >> 6] = mx;
  __syncthreads();
  #pragma unroll
  for (int i = 0; i < 16; ++i) mx = fmaxf(mx, rb[i]);
  float s = 0.f;
  #pragma unroll
  for (int i = 0; i < 32; ++i) { v[i] = __expf(v[i] - mx); s += v[i]; }
  #pragma unroll
  for (int m = 32; m >= 1; m >>= 1) s += __shfl_xor(s, m, 64);
  if ((tid & 63) == 0) sb[tid >> 6] = s;
  __syncthreads();
  s = 0.f;
  #pragma unroll
  for (int i = 0; i < 16; ++i) s += sb[i];
  float inv = 1.0f / s;
  #pragma unroll
  for (int i = 0; i < 32; ++i) {
    int j = tid + i*1024;
    if (j < VSZ) orow[j] = v[i] * inv;
  }
}

// =================================================================================
extern "C" void kernel_launch(void* const* d_in, const int* in_sizes, int n_in,
                              void* d_out, int out_size, void* d_ws, size_t ws_size,
                              hipStream_t stream)
{
  const int*   yt       = (const int*)  d_in[0];
  const float* h0       = (const float*)d_in[1];
  const float* c0       = (const float*)d_in[2];
  const float* h1       = (const float*)d_in[3];
  const float* c1       = (const float*)d_in[4];
  const float* enc      = (const float*)d_in[5];
  const float* c_prev   = (const float*)d_in[6];
  const float* embW     = (const float*)d_in[7];
  const float* pre_Wih  = (const float*)d_in[8];
  const float* pre_Whh  = (const float*)d_in[9];
  const float* pre_bih  = (const float*)d_in[10];
  const float* pre_bhh  = (const float*)d_in[11];
  const float* post_Wih = (const float*)d_in[12];
  const float* post_Whh = (const float*)d_in[13];
  const float* post_bih = (const float*)d_in[14];
  const float* post_bhh = (const float*)d_in[15];
  const float* att_W1   = (const float*)d_in[16];
  const float* att_b1   = (const float*)d_in[17];
  const float* att_W2   = (const float*)d_in[18];
  // d_in[19] = att_b2 cancels under softmax over Tx
  const float* mlp_W    = (const float*)d_in[20];
  const float* mlp_b    = (const float*)d_in[21];
  const float* bn_g     = (const float*)d_in[22];
  const float* bn_b     = (const float*)d_in[23];

  float* out   = (float*)d_out;
  float* o_h0  = out + (size_t)NB * VSZ;
  float* o_c0  = o_h0 + NB * HSZ;
  float* o_h1  = o_c0 + NB * HSZ;
  float* o_c1  = o_h1 + NB * HSZ;
  float* o_ctx = o_c1 + NB * HSZ;

  float* ws = (float*)d_ws;
  // early region (steps 1-5); zbuf (steps 6+) overlays dead early buffers.
  float* pre_cat  = ws;                         // @0          84,736
  float* gatesp   = ws + 84736;                 //             9*131,072 -> 1,264,384
  float* sprojp   = ws + 1264384;               //             131,072   -> 1,395,456
  float* mbuf     = ws + 1395456;               //             512
  float* sbuf     = ws + 1396480;               //             512       -> 1,397,504
  float* ctxp     = ws + 1397504;               //             262,144   -> 1,659,648
  float* post_cat = ws + 1921792;               //             98,304    -> 2,020,096
  unsigned short* W1b = (unsigned short*)(ws + 2020096);  //   262,144 u16 -> 2,151,168
  float* zbuf     = ws;                         // @0 overlay, 2,048,000 (step 6+)
  float* bnsc     = ws + 2151168;               //             32,000
  float* bnsh     = ws + 2183168;               //             32,000 -> 2,215,168 f (8.86 MB)

  // 1. prep: W1->bf16 + pre concat [emb | c_prev | h0]
  prep<<<459, 256, 0, stream>>>(yt, embW, c_prev, h0, att_W1, W1b, pre_cat);
  // 2. pre gates (fused ih+hh, split-K x9) + LSTM pointwise
  mfma_gemm128<0><<<dim3(G4/128, 9), 256, 0, stream>>>(
      pre_cat, KPRE, KPRE, pre_Wih, ESZ + NHD, ESZ + NHD, pre_Whh, HSZ,
      nullptr, gatesp, G4, 160, nullptr, nullptr, nullptr, nullptr);
  lstm_point2<<<NB*HSZ/256, 256, 0, stream>>>(gatesp, 9, pre_bih, pre_bhh, c0, o_h0, o_c0);
  // 3. sproj partials: s_i @ W1_s^T (split-K x4)
  mfma_gemm128<0><<<dim3(HALFD/128, 4), 256, 0, stream>>>(
      o_h0, HSZ, HSZ, att_W1 + NHD, NHD + HSZ, HSZ, att_W1 + NHD, NHD + HSZ,
      nullptr, sprojp, HALFD, 128, nullptr, nullptr, nullptr, nullptr);
  // 4. fused attention (scores + local softmax + context partials) + combine
  att_fused<<<512, 512, 0, stream>>>(enc, W1b, att_W2, sprojp, att_b1,
                                     mbuf, sbuf, ctxp);
  att_combine<<<NB*NHD/256, 256, 0, stream>>>(mbuf, sbuf, ctxp, o_h0, h1, o_ctx, post_cat);
  // 5. post gates (fused ih+hh, split-K x8) + LSTM pointwise
  mfma_gemm128<0><<<dim3(G4/128, 8), 256, 0, stream>>>(
      post_cat, KPOST, KPOST, post_Wih, HSZ + NHD, HSZ + NHD, post_Whh, HSZ,
      nullptr, gatesp, G4, 192, nullptr, nullptr, nullptr, nullptr);
  lstm_point2<<<NB*HSZ/256, 256, 0, stream>>>(gatesp, 8, post_bih, post_bhh, c1, o_h1, o_c1);
  // 6. classifier z = relu(h1 @ mlp_W^T + b) with fused BN-stats epilogue
  mfma_gemm128<4><<<dim3(VSZ/128, 1), 256, 0, stream>>>(
      o_h1, HSZ, HSZ, mlp_W, HSZ, HSZ, mlp_W, HSZ, mlp_b, zbuf, VSZ, 512,
      bn_g, bn_b, bnsc, bnsh);
  // 7. softmax over V (BN applied on the fly)
  softmax_v<<<NB, 1024, 0, stream>>>(zbuf, bnsc, bnsh, out);
}

// Round 10
// 141.298 us; speedup vs baseline: 2.5514x; 2.5514x over previous
//
#include <hip/hip_runtime.h>
#include <math.h>

#define DEVFN __device__ __forceinline__

typedef __attribute__((ext_vector_type(4))) float f32x4;
typedef __attribute__((ext_vector_type(8))) __bf16 bf16x8;
typedef __attribute__((ext_vector_type(8))) short short8v;

#define NB   64
#define TXD  1024
#define NHD  512
#define HSZ  512
#define ESZ  300
#define VSZ  32000
#define G4   (4*HSZ)           // 2048
#define KPRE (ESZ + NHD + HSZ) // 1324 (emb|c_prev|h0)
#define KPOST 1536             // (h0out|ctx|h1)
#define HALFD 512

DEVFN short f2bf(float f) {
  unsigned u = __float_as_uint(f);
  u = (u + 0x7fffu + ((u >> 16) & 1u)) >> 16;
  return (short)u;
}
DEVFN float sigm(float x) { return 1.0f / (1.0f + __expf(-x)); }

DEVFN short8v pack8(float4 a, float4 b) {
  short8v v;
  v[0]=f2bf(a.x); v[1]=f2bf(a.y); v[2]=f2bf(a.z); v[3]=f2bf(a.w);
  v[4]=f2bf(b.x); v[5]=f2bf(b.y); v[6]=f2bf(b.z); v[7]=f2bf(b.w);
  return v;
}
// async global->LDS, 16B per lane: dest = wave-uniform base + lane*16
DEVFN void gload16(const void* g, void* lds_base) {
  __builtin_amdgcn_global_load_lds(
      (const __attribute__((address_space(1))) unsigned int*)g,
      (__attribute__((address_space(3))) unsigned int*)lds_base, 16, 0, 0);
}

DEVFN float4 ldA4(const float* __restrict__ A, int lda, int row, int k, int Ka) {
  if (k >= Ka) { float4 z = {0.f,0.f,0.f,0.f}; return z; }
  return *(const float4*)(A + (size_t)row * lda + k);
}
DEVFN float4 ldB4(const float* __restrict__ B1, int ldb1, int split,
                  const float* __restrict__ B2, int ldb2, int row, int k, int Ka) {
  if (k >= Ka) { float4 z = {0.f,0.f,0.f,0.f}; return z; }
  if (k < split) return *(const float4*)(B1 + (size_t)row * ldb1 + k);
  return *(const float4*)(B2 + (size_t)row * ldb2 + (k - split));
}

// ---------- prep: W1->bf16 (blocks 0..127) | pre concat (128..458) --------------
__global__ __launch_bounds__(256)
void prep(const int* __restrict__ yt, const float* __restrict__ embW,
          const float* __restrict__ c_prev, const float* __restrict__ h0,
          const float* __restrict__ W1, unsigned short* __restrict__ W1b,
          float* __restrict__ cat)
{
  int b = blockIdx.x;
  if (b < 128) {
    int i = b * 256 + threadIdx.x;            // 0..32767, 8 elems each
    int c = i >> 6, kq = (i & 63) * 8;
    float4 a = *(const float4*)(W1 + (size_t)c * 1024 + kq);
    float4 bb = *(const float4*)(W1 + (size_t)c * 1024 + kq + 4);
    *(short8v*)(W1b + (size_t)c * 512 + kq) = pack8(a, bb);
  } else {
    int i = (b - 128) * 256 + threadIdx.x;    // < 64*1324
    if (i >= NB * KPRE) return;
    int n = i / KPRE, c = i - n * KPRE;
    float v;
    if (c < ESZ)            v = embW[(size_t)yt[n] * ESZ + c];
    else if (c < ESZ + NHD) v = c_prev[(size_t)n * NHD + (c - ESZ)];
    else                    v = h0[(size_t)n * HSZ + (c - ESZ - NHD)];
    cat[i] = v;
  }
}

// ---------- generic MFMA GEMM, 128-col tiles: C[64 x N] = A[64 x K] B[N x K]^T --
// Kslice multiple of 32. Split-K partial at C + ks*64*ldc.
// EPI: 0 none, 4 relu(x+bias1) + fused BN scale/shift outputs.
template<int EPI>
__global__ __launch_bounds__(256)
void mfma_gemm128(const float* __restrict__ A, int lda, int Ka,
                  const float* __restrict__ B1, int ldb1, int split,
                  const float* __restrict__ B2, int ldb2,
                  const float* __restrict__ bias1,
                  float* __restrict__ C, int ldc, int Kslice,
                  const float* __restrict__ gamma, const float* __restrict__ beta,
                  float* __restrict__ bnsc, float* __restrict__ bnsh)
{
  __shared__ __align__(16) short As[64][40];
  __shared__ __align__(16) short Bs[128][40];
  const int tid = threadIdx.x;
  const int w = tid >> 6, lane = tid & 63;
  const int wr = w >> 1, wc = w & 1;
  const int cl = lane & 15, g = lane >> 4;
  const int n0 = blockIdx.x * 128;
  const int ks = blockIdx.y;
  const int kbeg = ks * Kslice;
  const int kend = min(kbeg + Kslice, Ka);
  C += (size_t)ks * 64 * ldc;

  const f32x4 fz = {0.f,0.f,0.f,0.f};
  f32x4 acc[2][4];
  #pragma unroll
  for (int i = 0; i < 2; ++i)
    #pragma unroll
    for (int j = 0; j < 4; ++j) acc[i][j] = fz;

  const int sr  = tid >> 2;        // 0..63
  const int skc = (tid & 3) * 8;   // 0,8,16,24

  float4 ra0, ra1, rb0[2], rb1[2];
  ra0 = ldA4(A, lda, sr, kbeg + skc, Ka);
  ra1 = ldA4(A, lda, sr, kbeg + skc + 4, Ka);
  #pragma unroll
  for (int it = 0; it < 2; ++it) {
    rb0[it] = ldB4(B1, ldb1, split, B2, ldb2, n0 + sr + it*64, kbeg + skc, Ka);
    rb1[it] = ldB4(B1, ldb1, split, B2, ldb2, n0 + sr + it*64, kbeg + skc + 4, Ka);
  }

  for (int k0 = kbeg; k0 < kend; k0 += 32) {
    __syncthreads();
    *(short8v*)&As[sr][skc] = pack8(ra0, ra1);
    #pragma unroll
    for (int it = 0; it < 2; ++it)
      *(short8v*)&Bs[sr + it*64][skc] = pack8(rb0[it], rb1[it]);
    __syncthreads();
    if (k0 + 32 < kend) {
      ra0 = ldA4(A, lda, sr, k0 + 32 + skc, Ka);
      ra1 = ldA4(A, lda, sr, k0 + 32 + skc + 4, Ka);
      #pragma unroll
      for (int it = 0; it < 2; ++it) {
        rb0[it] = ldB4(B1, ldb1, split, B2, ldb2, n0 + sr + it*64, k0 + 32 + skc, Ka);
        rb1[it] = ldB4(B1, ldb1, split, B2, ldb2, n0 + sr + it*64, k0 + 32 + skc + 4, Ka);
      }
    }
    bf16x8 af[2], bfr[4];
    #pragma unroll
    for (int mi = 0; mi < 2; ++mi)
      af[mi] = *(const bf16x8*)&As[wr*32 + mi*16 + cl][g * 8];
    #pragma unroll
    for (int ni = 0; ni < 4; ++ni)
      bfr[ni] = *(const bf16x8*)&Bs[wc*64 + ni*16 + cl][g * 8];
    #pragma unroll
    for (int mi = 0; mi < 2; ++mi)
      #pragma unroll
      for (int ni = 0; ni < 4; ++ni)
        acc[mi][ni] = __builtin_amdgcn_mfma_f32_16x16x32_bf16(af[mi], bfr[ni], acc[mi][ni], 0, 0, 0);
  }

  float s1[4] = {0.f,0.f,0.f,0.f}, s2[4] = {0.f,0.f,0.f,0.f};
  #pragma unroll
  for (int ni = 0; ni < 4; ++ni) {
    int nn = n0 + wc*64 + ni*16 + cl;
    float b = (EPI == 4) ? bias1[nn] : 0.f;
    #pragma unroll
    for (int mi = 0; mi < 2; ++mi)
      #pragma unroll
      for (int r = 0; r < 4; ++r) {
        int m = wr*32 + mi*16 + g*4 + r;
        float v = acc[mi][ni][r];
        if (EPI == 4) v = fmaxf(v + b, 0.f);
        C[(size_t)m * ldc + nn] = v;
        if (EPI == 4) { s1[ni] += v; s2[ni] = fmaf(v, v, s2[ni]); }
      }
  }
  if (EPI == 4) {
    #pragma unroll
    for (int mm = 16; mm < 64; mm <<= 1)
      #pragma unroll
      for (int ni = 0; ni < 4; ++ni) {
        s1[ni] += __shfl_xor(s1[ni], mm, 64);
        s2[ni] += __shfl_xor(s2[ni], mm, 64);
      }
    float* red = (float*)As;   // 2KB, staging dead
    __syncthreads();
    if (g == 0) {
      #pragma unroll
      for (int ni = 0; ni < 4; ++ni) {
        int col = wc*64 + ni*16 + cl;
        red[(wr*128 + col)*2 + 0] = s1[ni];
        red[(wr*128 + col)*2 + 1] = s2[ni];
      }
    }
    __syncthreads();
    if (tid < 128) {
      int col = n0 + tid;
      float a1 = red[tid*2] + red[(128 + tid)*2];
      float a2 = red[tid*2 + 1] + red[(128 + tid)*2 + 1];
      float mean = a1 * (1.0f / NB);
      float var = a2 * (1.0f / NB) - mean * mean;
      float rr = rsqrtf(var + 1e-5f);
      float sc = gamma[col] * rr;
      bnsc[col] = sc;
      bnsh[col] = beta[col] - mean * sc;
    }
  }
}

// ---------- LSTM pointwise, summing np split-K gate partials --------------------
__global__ __launch_bounds__(256)
void lstm_point2(const float* __restrict__ gp, int np,
                 const float* __restrict__ bih, const float* __restrict__ bhh,
                 const float* __restrict__ c_old,
                 float* __restrict__ h_new, float* __restrict__ c_new)
{
  int i = blockIdx.x * 256 + threadIdx.x;   // < 64*512
  int n = i >> 9, k = i & 511;
  float g[4];
  #pragma unroll
  for (int j = 0; j < 4; ++j) {
    int idx = j * 512 + k;
    float s = bih[idx] + bhh[idx];
    for (int ks = 0; ks < np; ++ks)
      s += gp[((size_t)ks*64 + n) * G4 + idx];
    g[j] = s;
  }
  float c = sigm(g[1]) * c_old[i] + sigm(g[0]) * tanhf(g[2]);
  float h = sigm(g[3]) * tanhf(c);
  h_new[i] = h; c_new[i] = c;
}

// ---------- fused attention: 128 rows x ALL 512 cols, 8 waves -------------------
// 3-buffer counted-vmcnt pipeline (R5 schedule) + zero-conflict layout (R7/R8)
// + write-side bf16 A staging. grid 512 row-tiles; LDS 120KB, 1 block/CU.
// Layout (both tiles): line=row>>1 (128B), half=row&1, slot16 = q ^ (line&3).
// Per-wave VMEM/stage: A 2 reg-loads then B 4 gloads (FIFO; sched_barrier keeps
// order). vmcnt(4) = A arrived, vmcnt(6) = prev B landed. Raw s_barrier only.
__global__ __launch_bounds__(512)
void att_fused(const float* __restrict__ enc, const unsigned short* __restrict__ W1b,
               const float* __restrict__ W2, const float* __restrict__ sprojp,
               const float* __restrict__ b1,
               float* __restrict__ mbuf, float* __restrict__ sbuf,
               float* __restrict__ ctxp)
{
  __shared__ __align__(16) char smem[122880];  // A 3x8KB @0, B 3x32KB @24576
  const int tid = threadIdx.x;
  const int wid = tid >> 6, lane = tid & 63;
  const int wr = wid >> 2, wc = wid & 3;
  const int cl = lane & 15, g = lane >> 4;
  const int rt = blockIdx.x;
  const int r0 = rt << 7;
  const int n  = rt >> 3;

  // A write decode: row = tid>>2 (0..127), quad = tid&3
  const int a_row = tid >> 2;
  const int a_line = a_row >> 1;
  const int a_waddr = a_line*128 + (a_row & 1)*64 + (((tid & 3) ^ (a_line & 3)) << 4);
  // B gload lane decode (dest = base + lane*16, pre-swizzled source)
  const int b_r = ((lane >> 3) << 1) + ((lane >> 2) & 1);    // 0..15
  const int b_q = (((lane & 3) ^ ((lane >> 3) & 3)) << 3);   // bf16 units

  const f32x4 fz = {0.f,0.f,0.f,0.f};
  f32x4 acc[4][8];
  #pragma unroll
  for (int mi = 0; mi < 4; ++mi)
    #pragma unroll
    for (int ni = 0; ni < 8; ++ni) acc[mi][ni] = fz;

  float4 a_lo, a_hi;
  #define A_LOAD(tt) do { \
    const float* asrc = enc + (size_t)(r0 + a_row) * 512 + (tt) * 32 + (tid & 3) * 8; \
    a_lo = *(const float4*)asrc; a_hi = *(const float4*)(asrc + 4); } while (0)
  #define A_WRITE(buf) \
    *(short8v*)(smem + (buf) * 8192 + a_waddr) = pack8(a_lo, a_hi)
  #define STAGE_B(buf, tt) do { int k0 = (tt) * 32; \
    _Pragma("unroll") \
    for (int jj = 0; jj < 4; ++jj) { int j = (wid << 2) + jj; \
      gload16(W1b + (size_t)((j << 4) + b_r) * 512 + k0 + b_q, \
              smem + 24576 + (buf) * 32768 + (j << 10)); } } while (0)

  // prologue: buffers 0,1 staged; outstanding at loop top = A(1)2 + B(1)4
  A_LOAD(0);
  __builtin_amdgcn_sched_barrier(0);
  STAGE_B(0, 0);
  asm volatile("s_waitcnt vmcnt(4)" ::: "memory");   // A(0) arrived
  A_WRITE(0);
  A_LOAD(1);
  __builtin_amdgcn_sched_barrier(0);
  STAGE_B(1, 1);
  asm volatile("s_waitcnt vmcnt(6)" ::: "memory");   // B(0) landed
  asm volatile("s_waitcnt lgkmcnt(0)" ::: "memory"); // A(0) ds_write done
  __builtin_amdgcn_s_barrier();
  __builtin_amdgcn_sched_barrier(0);

  for (int t = 0; t < 16; ++t) {
    const int s = t % 3;
    if (t < 15) {
      asm volatile("s_waitcnt vmcnt(4)" ::: "memory"); // A(t+1) regs arrived
      A_WRITE((t + 1) % 3);
    }
    if (t < 14) {
      A_LOAD(t + 2);
      __builtin_amdgcn_sched_barrier(0);
      STAGE_B((t + 2) % 3, t + 2);
    }
    const char* Ab = smem + s * 8192;
    const char* Bb = smem + 24576 + s * 32768;
    bf16x8 af[4];
    #pragma unroll
    for (int mi = 0; mi < 4; ++mi) {
      int r = wr * 64 + mi * 16 + cl;
      af[mi] = *(const bf16x8*)(Ab + (r >> 1) * 128 + (r & 1) * 64
                                + ((g ^ ((r >> 1) & 3)) << 4));
    }
    #pragma unroll
    for (int ni = 0; ni < 8; ++ni) {
      int r = wc * 128 + ni * 16 + cl;
      bf16x8 bf = *(const bf16x8*)(Bb + (r >> 1) * 128 + (r & 1) * 64
                                   + ((g ^ ((r >> 1) & 3)) << 4));
      #pragma unroll
      for (int mi = 0; mi < 4; ++mi)
        acc[mi][ni] = __builtin_amdgcn_mfma_f32_16x16x32_bf16(af[mi], bf, acc[mi][ni], 0, 0, 0);
    }
    if (t < 15) {
      if (t < 14) asm volatile("s_waitcnt vmcnt(6)" ::: "memory");  // B(t+1) landed
      else        asm volatile("s_waitcnt vmcnt(0)" ::: "memory");  // drain last B
      asm volatile("s_waitcnt lgkmcnt(0)" ::: "memory");            // A ds_write done
      __builtin_amdgcn_s_barrier();
      __builtin_amdgcn_sched_barrier(0);
    }
  }
  #undef A_LOAD
  #undef A_WRITE
  #undef STAGE_B
  __syncthreads();

  // epilogue: relu(acc + sproj + b1) * W2, reduce over this wave's 128 cols
  float part[4][4] = {};
  #pragma unroll
  for (int ni = 0; ni < 8; ++ni) {
    int c = wc*128 + ni*16 + cl;
    float spv = b1[c];
    #pragma unroll
    for (int ks = 0; ks < 4; ++ks)
      spv += sprojp[((size_t)ks*64 + n) * HALFD + c];
    float w2 = W2[c];
    #pragma unroll
    for (int mi = 0; mi < 4; ++mi)
      #pragma unroll
      for (int r = 0; r < 4; ++r)
        part[mi][r] += fmaxf(acc[mi][ni][r] + spv, 0.f) * w2;
  }
  #pragma unroll
  for (int mm = 1; mm < 16; mm <<= 1)
    #pragma unroll
    for (int mi = 0; mi < 4; ++mi)
      #pragma unroll
      for (int r = 0; r < 4; ++r)
        part[mi][r] += __shfl_xor(part[mi][r], mm, 64);
  float* red = (float*)smem;            // [8][64] @0 (2 KB)
  float* sc  = (float*)(smem + 2048);   // [128]
  float* eV  = (float*)(smem + 2560);   // [128]
  if (cl == 0) {
    #pragma unroll
    for (int mi = 0; mi < 4; ++mi)
      #pragma unroll
      for (int r = 0; r < 4; ++r)
        red[wid*64 + mi*16 + g*4 + r] = part[mi][r];
  }
  __syncthreads();
  if (tid < 128) {
    int h = tid >> 6, idx = tid & 63;   // h = wr
    sc[tid] = red[(h*4 + 0)*64 + idx] + red[(h*4 + 1)*64 + idx]
            + red[(h*4 + 2)*64 + idx] + red[(h*4 + 3)*64 + idx];
  }
  __syncthreads();
  if (tid < 64) {
    float s0 = sc[tid], s1v = sc[tid + 64];
    float M = fmaxf(s0, s1v);
    #pragma unroll
    for (int mm = 32; mm >= 1; mm >>= 1) M = fmaxf(M, __shfl_xor(M, mm, 64));
    float e0 = __expf(s0 - M), e1 = __expf(s1v - M);
    eV[tid] = e0; eV[tid + 64] = e1;
    float S = e0 + e1;
    #pragma unroll
    for (int mm = 32; mm >= 1; mm >>= 1) S += __shfl_xor(S, mm, 64);
    if (tid == 0) { mbuf[rt] = M; sbuf[rt] = S; }
  }
  __syncthreads();

  // pass 2: ctx_rt[c] = sum_{t<128} eV[t] * enc[r0+t][c]  (rows L2-hot)
  f32x4* red4 = (f32x4*)(smem + 24576);   // [4][128] f32x4 (8 KB), staging dead
  {
    const int cgrp = tid & 127, tq = tid >> 7;   // tq 0..3, 32 rows each
    const float* ebase = enc + (size_t)r0 * 512 + (cgrp << 2);
    f32x4 a4 = fz;
    #pragma unroll 8
    for (int tt = 0; tt < 32; ++tt) {
      int t = tq*32 + tt;
      float et = eV[t];
      float4 x = *(const float4*)(ebase + (size_t)t * 512);
      a4[0] = fmaf(et, x.x, a4[0]);
      a4[1] = fmaf(et, x.y, a4[1]);
      a4[2] = fmaf(et, x.z, a4[2]);
      a4[3] = fmaf(et, x.w, a4[3]);
    }
    red4[tq*128 + cgrp] = a4;
  }
  __syncthreads();
  if (tid < 128) {
    f32x4 s4 = red4[tid];
    f32x4 b4 = red4[128 + tid];
    f32x4 c4 = red4[256 + tid];
    f32x4 d4 = red4[384 + tid];
    f32x4 o4;
    #pragma unroll
    for (int i = 0; i < 4; ++i) o4[i] = s4[i] + b4[i] + c4[i] + d4[i];
    *(f32x4*)(ctxp + (size_t)rt * 512 + tid*4) = o4;
  }
}

// ---------- combine 8 tile-partials per n -> context, post concat ---------------
__global__ __launch_bounds__(256)
void att_combine(const float* __restrict__ mbuf, const float* __restrict__ sbuf,
                 const float* __restrict__ ctxp, const float* __restrict__ h0out,
                 const float* __restrict__ h1in,
                 float* __restrict__ ctx_out, float* __restrict__ cat)
{
  int i = blockIdx.x * 256 + threadIdx.x;   // < 64*512
  int n = i >> 9, c = i & 511;
  float M = -1e30f;
  #pragma unroll
  for (int b = 0; b < 8; ++b) M = fmaxf(M, mbuf[n*8 + b]);
  float S = 0.f, ctx = 0.f;
  #pragma unroll
  for (int b = 0; b < 8; ++b) {
    float w = __expf(mbuf[n*8 + b] - M);
    S = fmaf(sbuf[n*8 + b], w, S);
    ctx = fmaf(ctxp[(size_t)(n*8 + b)*512 + c], w, ctx);
  }
  ctx /= S;
  ctx_out[i] = ctx;
  cat[(size_t)n * KPOST + c] = h0out[i];
  cat[(size_t)n * KPOST + HSZ + c] = ctx;
  cat[(size_t)n * KPOST + 2*HSZ + c] = h1in[i];
}

// ---------- final softmax over V: z cached in registers (1 read pass) -----------
__global__ __launch_bounds__(1024)
void softmax_v(const float* __restrict__ z, const float* __restrict__ scale,
               const float* __restrict__ shift, float* __restrict__ out)
{
  int n = blockIdx.x, tid = threadIdx.x;
  const float* zr = z + (size_t)n * VSZ;
  float* orow = out + (size_t)n * VSZ;
  __shared__ float rb[16];
  __shared__ float sb[16];
  float v[32]; float mx = -1e30f;
  #pragma unroll
  for (int i = 0; i < 32; ++i) {
    int j = tid + i*1024;
    v[i] = (j < VSZ) ? fmaf(zr[j], scale[j], shift[j]) : -1e30f;
    mx = fmaxf(mx, v[i]);
  }
  #pragma unroll
  for (int m = 32; m >= 1; m >>= 1) mx = fmaxf(mx, __shfl_xor(mx, m, 64));
  if ((tid & 63) == 0) rb[tid >> 6] = mx;
  __syncthreads();
  #pragma unroll
  for (int i = 0; i < 16; ++i) mx = fmaxf(mx, rb[i]);
  float s = 0.f;
  #pragma unroll
  for (int i = 0; i < 32; ++i) { v[i] = __expf(v[i] - mx); s += v[i]; }
  #pragma unroll
  for (int m = 32; m >= 1; m >>= 1) s += __shfl_xor(s, m, 64);
  if ((tid & 63) == 0) sb[tid >> 6] = s;
  __syncthreads();
  s = 0.f;
  #pragma unroll
  for (int i = 0; i < 16; ++i) s += sb[i];
  float inv = 1.0f / s;
  #pragma unroll
  for (int i = 0; i < 32; ++i) {
    int j = tid + i*1024;
    if (j < VSZ) orow[j] = v[i] * inv;
  }
}

// =================================================================================
extern "C" void kernel_launch(void* const* d_in, const int* in_sizes, int n_in,
                              void* d_out, int out_size, void* d_ws, size_t ws_size,
                              hipStream_t stream)
{
  const int*   yt       = (const int*)  d_in[0];
  const float* h0       = (const float*)d_in[1];
  const float* c0       = (const float*)d_in[2];
  const float* h1       = (const float*)d_in[3];
  const float* c1       = (const float*)d_in[4];
  const float* enc      = (const float*)d_in[5];
  const float* c_prev   = (const float*)d_in[6];
  const float* embW     = (const float*)d_in[7];
  const float* pre_Wih  = (const float*)d_in[8];
  const float* pre_Whh  = (const float*)d_in[9];
  const float* pre_bih  = (const float*)d_in[10];
  const float* pre_bhh  = (const float*)d_in[11];
  const float* post_Wih = (const float*)d_in[12];
  const float* post_Whh = (const float*)d_in[13];
  const float* post_bih = (const float*)d_in[14];
  const float* post_bhh = (const float*)d_in[15];
  const float* att_W1   = (const float*)d_in[16];
  const float* att_b1   = (const float*)d_in[17];
  const float* att_W2   = (const float*)d_in[18];
  // d_in[19] = att_b2 cancels under softmax over Tx
  const float* mlp_W    = (const float*)d_in[20];
  const float* mlp_b    = (const float*)d_in[21];
  const float* bn_g     = (const float*)d_in[22];
  const float* bn_b     = (const float*)d_in[23];

  float* out   = (float*)d_out;
  float* o_h0  = out + (size_t)NB * VSZ;
  float* o_c0  = o_h0 + NB * HSZ;
  float* o_h1  = o_c0 + NB * HSZ;
  float* o_c1  = o_h1 + NB * HSZ;
  float* o_ctx = o_c1 + NB * HSZ;

  float* ws = (float*)d_ws;
  // early region (steps 1-5); zbuf (steps 6+) overlays dead early buffers.
  float* pre_cat  = ws;                         // @0          84,736
  float* gatesp   = ws + 84736;                 //             9*131,072 -> 1,264,384
  float* sprojp   = ws + 1264384;               //             131,072   -> 1,395,456
  float* mbuf     = ws + 1395456;               //             512
  float* sbuf     = ws + 1396480;               //             512       -> 1,397,504
  float* ctxp     = ws + 1397504;               //             262,144   -> 1,659,648
  float* post_cat = ws + 1921792;               //             98,304    -> 2,020,096
  unsigned short* W1b = (unsigned short*)(ws + 2020096);  //   262,144 u16 -> 2,151,168
  float* zbuf     = ws;                         // @0 overlay, 2,048,000 (step 6+)
  float* bnsc     = ws + 2151168;               //             32,000
  float* bnsh     = ws + 2183168;               //             32,000 -> 2,215,168 f (8.86 MB)

  // 1. prep: W1->bf16 + pre concat [emb | c_prev | h0]
  prep<<<459, 256, 0, stream>>>(yt, embW, c_prev, h0, att_W1, W1b, pre_cat);
  // 2. pre gates (fused ih+hh, split-K x9) + LSTM pointwise
  mfma_gemm128<0><<<dim3(G4/128, 9), 256, 0, stream>>>(
      pre_cat, KPRE, KPRE, pre_Wih, ESZ + NHD, ESZ + NHD, pre_Whh, HSZ,
      nullptr, gatesp, G4, 160, nullptr, nullptr, nullptr, nullptr);
  lstm_point2<<<NB*HSZ/256, 256, 0, stream>>>(gatesp, 9, pre_bih, pre_bhh, c0, o_h0, o_c0);
  // 3. sproj partials: s_i @ W1_s^T (split-K x4)
  mfma_gemm128<0><<<dim3(HALFD/128, 4), 256, 0, stream>>>(
      o_h0, HSZ, HSZ, att_W1 + NHD, NHD + HSZ, HSZ, att_W1 + NHD, NHD + HSZ,
      nullptr, sprojp, HALFD, 128, nullptr, nullptr, nullptr, nullptr);
  // 4. fused attention (scores + local softmax + context partials) + combine
  att_fused<<<512, 512, 0, stream>>>(enc, W1b, att_W2, sprojp, att_b1,
                                     mbuf, sbuf, ctxp);
  att_combine<<<NB*NHD/256, 256, 0, stream>>>(mbuf, sbuf, ctxp, o_h0, h1, o_ctx, post_cat);
  // 5. post gates (fused ih+hh, split-K x8) + LSTM pointwise
  mfma_gemm128<0><<<dim3(G4/128, 8), 256, 0, stream>>>(
      post_cat, KPOST, KPOST, post_Wih, HSZ + NHD, HSZ + NHD, post_Whh, HSZ,
      nullptr, gatesp, G4, 192, nullptr, nullptr, nullptr, nullptr);
  lstm_point2<<<NB*HSZ/256, 256, 0, stream>>>(gatesp, 8, post_bih, post_bhh, c1, o_h1, o_c1);
  // 6. classifier z = relu(h1 @ mlp_W^T + b) with fused BN-stats epilogue
  mfma_gemm128<4><<<dim3(VSZ/128, 1), 256, 0, stream>>>(
      o_h1, HSZ, HSZ, mlp_W, HSZ, HSZ, mlp_W, HSZ, mlp_b, zbuf, VSZ, 512,
      bn_g, bn_b, bnsc, bnsh);
  // 7. softmax over V (BN applied on the fly)
  softmax_v<<<NB, 1024, 0, stream>>>(zbuf, bnsc, bnsh, out);
}